// Round 13
// baseline (717.751 us; speedup 1.0000x reference)
//
#include <hip/hip_runtime.h>
#include <stdint.h>

#define MDIM 8192
#define NDIM 16384
#define KDIM 4096
#define NT   64          // K-steps of 64

typedef __attribute__((ext_vector_type(4)))  int i32x4;
typedef __attribute__((ext_vector_type(16))) int i32x16;

__device__ __forceinline__ void gload_lds16(const void* g, void* l) {
    __builtin_amdgcn_global_load_lds(
        (const __attribute__((address_space(1))) void*)g,
        (__attribute__((address_space(3))) void*)l,
        16, 0, 0);
}

__device__ __forceinline__ i32x16 MFMA32(i32x4 a, i32x4 b, i32x16 c) {
    return __builtin_amdgcn_mfma_i32_32x32x32_i8(a, b, c, 0, 0, 0);
}

// ---------------- quantization kernels (unchanged, round-6 verified) ----------------

__global__ __launch_bounds__(256)
void quant_x_kernel(const float* __restrict__ x, int8_t* __restrict__ xq,
                    float* __restrict__ sx) {
    const int row = (int)blockIdx.x;
    const float* xr = x + (long)row * KDIM;
    const int t = threadIdx.x;
    float v[16];
#pragma unroll
    for (int i = 0; i < 4; ++i)
        *(float4*)&v[i * 4] = ((const float4*)xr)[t + 256 * i];
    float m = 0.f;
#pragma unroll
    for (int i = 0; i < 16; ++i) m = fmaxf(m, fabsf(v[i]));
#pragma unroll
    for (int off = 32; off >= 1; off >>= 1) m = fmaxf(m, __shfl_xor(m, off));
    __shared__ float red[4];
    if ((t & 63) == 0) red[t >> 6] = m;
    __syncthreads();
    m = fmaxf(fmaxf(red[0], red[1]), fmaxf(red[2], red[3]));
    m = fmaxf(m, 1e-20f);
    const float inv = 127.0f / m;
    if (t == 0) sx[row] = m * (1.0f / 127.0f);
    int* qo = (int*)(xq + (long)row * KDIM);
#pragma unroll
    for (int i = 0; i < 4; ++i) {
        union { int8_t c[4]; int w; } o;
#pragma unroll
        for (int j = 0; j < 4; ++j)
            o.c[j] = (int8_t)__float2int_rn(v[i * 4 + j] * inv);
        qo[t + 256 * i] = o.w;
    }
}

__global__ __launch_bounds__(256)
void quant_w_kernel(const int* __restrict__ q, const int* __restrict__ zp,
                    int8_t* __restrict__ wq) {
    const long i = (long)blockIdx.x * 256 + threadIdx.x;
    const long e = i * 16;
    const int o = (int)(e >> 12);          // KDIM = 4096
    const int z = zp[o];
    union { int8_t c[16]; int4 v; } r;
#pragma unroll
    for (int b = 0; b < 4; ++b) {
        int4 a = ((const int4*)(q + e))[b];
        r.c[b * 4 + 0] = (int8_t)(a.x - z);
        r.c[b * 4 + 1] = (int8_t)(a.y - z);
        r.c[b * 4 + 2] = (int8_t)(a.z - z);
        r.c[b * 4 + 3] = (int8_t)(a.w - z);
    }
    *(int4*)(wq + e) = r.v;
}

// ---- 256x256 8-wave int8 GEMM, 32x32x32 MFMA, triple-buffered (round-6 ledger) ----
// C[m,n] = scale[n] * sx[m] * sum_k xq[m,k] * wq[n,k]   (i32 accum, exact)
// LDS: 3 bufs x (A plane 16 KB + B plane 16 KB) = 96 KB; XOR chunk swizzle
// sc = c ^ ((r>>1)&3) via pre-swizzled global source, linear DMA dest.
// Wave tile 128x64 = 4 m-tiles x 2 n-tiles of 32x32; per K-step (K=64) each
// tile does 2 MFMAs (ks=0,1). Reads/tile/wave: A 4x2 + B 2x2 = 12 b128 (same
// as 16x16 variant); MFMA count HALVED (16 vs 32) at the better 32x32 rate.
// 32-lane frag reads span 32 rows -> 16 banks x 2-way (free, m136).
// Schedule/ledger = round-6 verified (absmax 28): 2 phases/K-step, stage
// 2 K-steps ahead, vmcnt(2) counted wait, ONE barrier/K-step.
// Block mapping (round-3 verified): round = 256 blocks covers ALL 32 A-panels
// x 8 B-panels; inputs (100 MB int8) L3-resident.

__global__ __launch_bounds__(512, 2)
void gemm_i8_kernel(const int8_t* __restrict__ A, const int8_t* __restrict__ Wt,
                    const float* __restrict__ scale, const float* __restrict__ sx,
                    float* __restrict__ C) {
    __shared__ int8_t lds[3 * 32768];

    const int wg = (int)blockIdx.x;
    const int rr = wg >> 8;                   // round 0..7
    const int ii = wg & 255;
    const int bm = ii & 31;                   // all 32 A-panels each round
    const int bn = rr * 8 + (ii >> 5);        // 8 fresh B-panels per round

    const int tid  = threadIdx.x;
    const int lane = tid & 63;
    const int wid  = tid >> 6;
    const int wm   = wid >> 2;        // 0..1 (128 rows)
    const int wn   = wid & 3;         // 0..3 (64 cols)
    const int l31  = lane & 31;
    const int lh   = lane >> 5;       // 0..1

    // 32x32 frag read: row r = base + l31, chunk c = ks*2 + lh, sc = c ^ ((l31>>1)&3)
    const int xnib = (l31 >> 1) & 3;

    // staging: thread covers plane slots s0 = tid, s1 = 512+tid (16 KB plane)
    const int s0 = tid, s1 = 512 + tid;
    const int soff0 = (s0 >> 2) * KDIM + ((((s0 & 3) ^ ((s0 >> 3) & 3))) << 4);
    const int soff1 = (s1 >> 2) * KDIM + ((((s1 & 3) ^ ((s1 >> 3) & 3))) << 4);
    const int d0 = s0 * 16, d1 = s1 * 16;

    const int8_t* Ab = A  + (long)bm * 256 * KDIM;
    const int8_t* Wb = Wt + (long)bn * 256 * KDIM;

#define STAGE(bb, P, base, tt)                                                      \
    do {                                                                            \
        gload_lds16((base) + soff0 + (tt) * 64, &lds[(bb) + (P) * 16384 + d0]);     \
        gload_lds16((base) + soff1 + (tt) * 64, &lds[(bb) + (P) * 16384 + d1]);     \
    } while (0)

// A frags: m-tiles MTB, MTB+1 (x ks 0,1) from buffer BB
#define RDA2(DST, BB, MTB)                                                          \
    _Pragma("unroll")                                                               \
    for (int m_ = 0; m_ < 2; ++m_)                                                  \
        _Pragma("unroll")                                                           \
        for (int k_ = 0; k_ < 2; ++k_)                                              \
            DST[m_ * 2 + k_] = *(const i32x4*)&lds[(BB) +                           \
                (wm * 128 + ((MTB) + m_) * 32 + l31) * 64 +                         \
                (((k_ * 2 + lh) ^ xnib) << 4)];

// B frags: n-tiles 0,1 (x ks 0,1) from buffer BB
#define RDB(DST, BB)                                                                \
    _Pragma("unroll")                                                               \
    for (int n_ = 0; n_ < 2; ++n_)                                                  \
        _Pragma("unroll")                                                           \
        for (int k_ = 0; k_ < 2; ++k_)                                              \
            DST[n_ * 2 + k_] = *(const i32x4*)&lds[(BB) + 16384 +                   \
                (wn * 64 + n_ * 32 + l31) * 64 +                                    \
                (((k_ * 2 + lh) ^ xnib) << 4)];

// 8 MFMAs: m-tiles MB,MB+1 x n-tiles 0,1 x ks 0,1
#define MFH(MB, AS, BS)                                                             \
    do {                                                                            \
        __builtin_amdgcn_sched_barrier(0);                                          \
        __builtin_amdgcn_s_setprio(1);                                              \
        _Pragma("unroll")                                                           \
        for (int m_ = 0; m_ < 2; ++m_)                                              \
            _Pragma("unroll")                                                       \
            for (int n_ = 0; n_ < 2; ++n_)                                          \
                _Pragma("unroll")                                                   \
                for (int k_ = 0; k_ < 2; ++k_)                                      \
                    acc[(MB) + m_][n_] = MFMA32(AS[m_ * 2 + k_], BS[n_ * 2 + k_],   \
                                                acc[(MB) + m_][n_]);                \
        __builtin_amdgcn_s_setprio(0);                                              \
        __builtin_amdgcn_sched_barrier(0);                                          \
    } while (0)

    i32x16 acc[4][2];
#pragma unroll
    for (int i = 0; i < 4; ++i)
#pragma unroll
        for (int j = 0; j < 2; ++j)
#pragma unroll
            for (int r = 0; r < 16; ++r) acc[i][j][r] = 0;

    i32x4 aS0[4], aHi[4], bSA[4], bSB[4];
    int b0 = 0, b1 = 32768, b2 = 65536;

    // prologue: stage steps 0 and 1; tile-0 landed (vmcnt(4)); pre-read phase-A frags
    STAGE(b0, 0, Ab, 0); STAGE(b0, 1, Wb, 0);
    STAGE(b1, 0, Ab, 1); STAGE(b1, 1, Wb, 1);
    asm volatile("s_waitcnt vmcnt(4)" ::: "memory");
    __builtin_amdgcn_s_barrier();
    RDA2(aS0, b0, 0);
    RDB(bSA, b0);

#define KSTEP(T, BCUR, BNXT)                                                        \
    do {                                                                            \
        const bool pf_ = (T) < NT - 2;                                              \
        /* phase A: read A m-tiles 2,3 (cur); stage A(T+2); MFMA m 0,1 */           \
        RDA2(aHi, b0, 2);                                                           \
        if (pf_) { STAGE(b2, 0, Ab, (T) + 2); }                                     \
        MFH(0, aS0, BCUR);                                                          \
        /* phase B: sync; read A m0,1 + B of T+1; stage B(T+2); MFMA m 2,3 */       \
        asm volatile("s_waitcnt lgkmcnt(0)" ::: "memory");                          \
        if (pf_) asm volatile("s_waitcnt vmcnt(2)" ::: "memory");                   \
        else     asm volatile("s_waitcnt vmcnt(0)" ::: "memory");                   \
        __builtin_amdgcn_s_barrier();                                               \
        RDA2(aS0, b1, 0);                                                           \
        RDB(BNXT, b1);                                                              \
        if (pf_) { STAGE(b2, 1, Wb, (T) + 2); }                                     \
        MFH(2, aHi, BCUR);                                                          \
        const int tb_ = b0; b0 = b1; b1 = b2; b2 = tb_;                             \
    } while (0)

    for (int t = 0; t < NT; t += 2) {
        KSTEP(t,     bSA, bSB);
        KSTEP(t + 1, bSB, bSA);
    }
#undef KSTEP
#undef STAGE
#undef RDA2
#undef RDB
#undef MFH

    // epilogue: 32x32 D mapping (m74/m101-verified):
    // col = lane&31, row = (reg&3) + 8*(reg>>2) + 4*(lane>>5)
    const long rowA0 = (long)bm * 256 + wm * 128;
    const int  colB0 = bn * 256 + wn * 64;
    float scj[2];
#pragma unroll
    for (int n = 0; n < 2; ++n) scj[n] = scale[colB0 + n * 32 + l31];
#pragma unroll
    for (int mt = 0; mt < 4; ++mt) {
#pragma unroll
        for (int g = 0; g < 4; ++g) {
            const long rb = rowA0 + mt * 32 + g * 8 + lh * 4;
            const float4 s4 = *(const float4*)(sx + rb);
#pragma unroll
            for (int n = 0; n < 2; ++n) {
                float* cp = C + rb * NDIM + colB0 + n * 32 + l31;
                cp[0 * (long)NDIM] = (float)acc[mt][n][g * 4 + 0] * scj[n] * s4.x;
                cp[1 * (long)NDIM] = (float)acc[mt][n][g * 4 + 1] * scj[n] * s4.y;
                cp[2 * (long)NDIM] = (float)acc[mt][n][g * 4 + 2] * scj[n] * s4.z;
                cp[3 * (long)NDIM] = (float)acc[mt][n][g * 4 + 3] * scj[n] * s4.w;
            }
        }
    }
}

// ---------------- safety fallback (no workspace needed, fp32, slow) ----------------

__global__ __launch_bounds__(256)
void fallback_kernel(const float* __restrict__ x, const int* __restrict__ q,
                     const float* __restrict__ scale, const int* __restrict__ zp,
                     float* __restrict__ out) {
    __shared__ float sA[64][17];
    __shared__ float sB[64][17];
    const int bn = (int)blockIdx.x % (NDIM / 64);
    const int bm = (int)blockIdx.x / (NDIM / 64);
    const int t  = threadIdx.x;
    const int tx = t & 15, ty = t >> 4;
    const long rowA = (long)bm * 64, rowB = (long)bn * 64;
    float acc[4][4] = {};
    for (int k0 = 0; k0 < KDIM; k0 += 16) {
#pragma unroll
        for (int i = 0; i < 4; ++i) {
            const int e = t + i * 256;
            const int r = e >> 4, c = e & 15;
            sA[r][c] = x[(rowA + r) * KDIM + k0 + c];
            const int o = (int)rowB + r;
            sB[r][c] = (float)(q[(long)o * KDIM + k0 + c] - zp[o]) * scale[o];
        }
        __syncthreads();
#pragma unroll
        for (int kk = 0; kk < 16; ++kk) {
            float a[4], b[4];
#pragma unroll
            for (int i = 0; i < 4; ++i) a[i] = sA[ty * 4 + i][kk];
#pragma unroll
            for (int j = 0; j < 4; ++j) b[j] = sB[tx * 4 + j][kk];
#pragma unroll
            for (int i = 0; i < 4; ++i)
#pragma unroll
                for (int j = 0; j < 4; ++j) acc[i][j] += a[i] * b[j];
        }
        __syncthreads();
    }
#pragma unroll
    for (int i = 0; i < 4; ++i) {
        const long r = rowA + ty * 4 + i;
#pragma unroll
        for (int j = 0; j < 4; ++j)
            out[r * NDIM + rowB + tx * 4 + j] = acc[i][j];
    }
}

// ---------------- launch ----------------

extern "C" void kernel_launch(void* const* d_in, const int* in_sizes, int n_in,
                              void* d_out, int out_size, void* d_ws, size_t ws_size,
                              hipStream_t stream) {
    const float* x     = (const float*)d_in[0];
    const int*   qw    = (const int*)d_in[1];
    const float* scale = (const float*)d_in[2];
    const int*   zp    = (const int*)d_in[3];
    float*       out   = (float*)d_out;

    const size_t needA  = (size_t)MDIM * KDIM;          // 33.5 MB int8
    const size_t needW  = (size_t)NDIM * KDIM;          // 67.1 MB int8
    const size_t needSx = (size_t)MDIM * sizeof(float); // 32 KB

    if (ws_size >= needA + needW + needSx) {
        int8_t* xq = (int8_t*)d_ws;
        int8_t* wq = xq + needA;
        float*  sx = (float*)((char*)d_ws + needA + needW);
        quant_x_kernel<<<MDIM, 256, 0, stream>>>(x, xq, sx);
        quant_w_kernel<<<(NDIM * (KDIM / 16)) / 256, 256, 0, stream>>>(qw, zp, wq);
        gemm_i8_kernel<<<(MDIM / 256) * (NDIM / 256), 512, 0, stream>>>(xq, wq, scale, sx, out);
    } else {
        fallback_kernel<<<(MDIM / 64) * (NDIM / 64), 256, 0, stream>>>(x, qw, scale, zp, out);
    }
}